// Round 20
// baseline (1281.793 us; speedup 1.0000x reference)
//
#include <hip/hip_runtime.h>
#include <hip/hip_bf16.h>
#include <cstdint>
#include <cstddef>

#define Bsz  256
#define Tn   4096
#define In   8
#define Hn   32
#define TGTn 8

// sigmoid(p) = 1/(1+exp2(ALPHA*p)) with ALPHA = -log2(e)
// tanh path:  exp(2y) = exp2(BETA*y)  with BETA  = 2*log2(e)
#define ALPHA (-1.44269504088896341f)
#define BETA  ( 2.88539008177792682f)

#if __has_builtin(__builtin_amdgcn_exp2f)
__device__ __forceinline__ float exp2f_fast(float x) { return __builtin_amdgcn_exp2f(x); }
#else
__device__ __forceinline__ float exp2f_fast(float x) { return __expf(x * 0.69314718056f); }
#endif
__device__ __forceinline__ float rcpf(float x) { return __builtin_amdgcn_rcpf(x); }

// DPP row_ror:N via builtin (compiler inserts all DPP hazard wait-states).
// Used in BOTH the init probe and the hot loop -> permutation matches by
// construction.
template<int N>
__device__ __forceinline__ float dpp_ror(float x) {
    int xi = __float_as_int(x);
    int r = __builtin_amdgcn_update_dpp(xi, xi, 0x120 + N, 0xF, 0xF, false);
    return __int_as_float(r);
}

// x_l + x_{l^16}: sum of both permlane16_swap outputs (order-proof).
__device__ __forceinline__ float halfsum16(float x) {
    auto r = __builtin_amdgcn_permlane16_swap(__float_as_int(x), __float_as_int(x),
                                              false, false);
    return __int_as_float((int)r[0]) + __int_as_float((int)r[1]);
}

// W = w_ih @ E : [96,8] (raw; scaling applied at gru init)
__global__ void fuse_wih_kernel(const float* __restrict__ w_ih,
                                const float* __restrict__ E,
                                float* __restrict__ Wf) {
    int tid = threadIdx.x;                // 768 threads
    int g = tid >> 3, i = tid & 7;
    float acc = 0.f;
#pragma unroll
    for (int k = 0; k < Hn; ++k)
        acc = fmaf(w_ih[g * Hn + k], E[k * In + i], acc);
    Wf[g * In + i] = acc;
}

// m-th h-term: PLAIN fma reading the pre-rotated (independent) hr##M.
#define HT(M)                                                                        \
    ar  = fmaf(hr##M, whr##M, ar);                                                   \
    az  = fmaf(hr##M, whz##M, az);                                                   \
    anh = fmaf(hr##M, whn##M, anh);

// One GRU step. XA/XB = x[s] (uniform float4 pair); XRA/XRB = slot refilled
// with x[s+4] when DO_REFILL. hsrc = h[16*rowpar + (lane&15)] per lane.
#define GRU_STEP(XA, XB, XRA, XRB, DO_REFILL)                                        \
  {                                                                                  \
    /* x-dots: full 8 per lane (r/z pre-halved for the halfsum; n full) */           \
    float ar = br_h, az = bz_h, anx = bxn_f, anh = bhn_h;                            \
    ar  = fmaf(XA.x, wxr0, ar);  ar  = fmaf(XA.y, wxr1, ar);                         \
    ar  = fmaf(XA.z, wxr2, ar);  ar  = fmaf(XA.w, wxr3, ar);                         \
    ar  = fmaf(XB.x, wxr4, ar);  ar  = fmaf(XB.y, wxr5, ar);                         \
    ar  = fmaf(XB.z, wxr6, ar);  ar  = fmaf(XB.w, wxr7, ar);                         \
    az  = fmaf(XA.x, wxz0, az);  az  = fmaf(XA.y, wxz1, az);                         \
    az  = fmaf(XA.z, wxz2, az);  az  = fmaf(XA.w, wxz3, az);                         \
    az  = fmaf(XB.x, wxz4, az);  az  = fmaf(XB.y, wxz5, az);                         \
    az  = fmaf(XB.z, wxz6, az);  az  = fmaf(XB.w, wxz7, az);                         \
    anx = fmaf(XA.x, wxn0, anx); anx = fmaf(XA.y, wxn1, anx);                        \
    anx = fmaf(XA.z, wxn2, anx); anx = fmaf(XA.w, wxn3, anx);                        \
    anx = fmaf(XB.x, wxn4, anx); anx = fmaf(XB.y, wxn5, anx);                        \
    anx = fmaf(XB.z, wxn6, anx); anx = fmaf(XB.w, wxn7, anx);                        \
    /* 15 INDEPENDENT rotations of hsrc (pipelined DPP movs; r19's serial    */      \
    /* chain exposed ~26cyc/link dependent latency — this avoids it), then   */      \
    /* 48 plain fmas (r16 paid 48 quarter-rate DPP-fmacs here)               */      \
    float hr1  = dpp_ror<1>(hsrc),  hr2  = dpp_ror<2>(hsrc),  hr3  = dpp_ror<3>(hsrc); \
    float hr4  = dpp_ror<4>(hsrc),  hr5  = dpp_ror<5>(hsrc),  hr6  = dpp_ror<6>(hsrc); \
    float hr7  = dpp_ror<7>(hsrc),  hr8  = dpp_ror<8>(hsrc),  hr9  = dpp_ror<9>(hsrc); \
    float hr10 = dpp_ror<10>(hsrc), hr11 = dpp_ror<11>(hsrc), hr12 = dpp_ror<12>(hsrc);\
    float hr13 = dpp_ror<13>(hsrc), hr14 = dpp_ror<14>(hsrc), hr15 = dpp_ror<15>(hsrc);\
    ar  = fmaf(hsrc, whr0, ar);                                                      \
    az  = fmaf(hsrc, whz0, az);                                                      \
    anh = fmaf(hsrc, whn0, anh);                                                     \
    HT(1)  HT(2)  HT(3)  HT(4)  HT(5)  HT(6)  HT(7)  HT(8)                           \
    HT(9)  HT(10) HT(11) HT(12) HT(13) HT(14) HT(15)                                 \
    float cr  = halfsum16(ar);            /* ALPHA*(xdot+hdot+bias) */               \
    float cz  = halfsum16(az);                                                       \
    float chn = halfsum16(anh);           /* BETA*(hdot+b_hn)       */               \
    float r = rcpf(1.f + exp2f_fast(cr));                                            \
    float z = rcpf(1.f + exp2f_fast(cz));                                            \
    float e = exp2f_fast(__builtin_fmaf(r, chn, anx));                               \
    float u = rcpf(e + 1.f);                                                         \
    float n = __builtin_fmaf(-2.f, u, 1.f);                                          \
    hj = __builtin_fmaf(z, hj - n, n);                                               \
    /* redistribute: hsrc = h[16*rowpar + (lane&15)] (probed selection) */           \
    {                                                                                \
        auto rr = __builtin_amdgcn_permlane32_swap(__float_as_int(hj),               \
                                                   __float_as_int(hj),               \
                                                   false, false);                    \
        float s0 = __int_as_float((int)rr[0]);                                       \
        float s1 = __int_as_float((int)rr[1]);                                       \
        hsrc = pickr1 ? s1 : s0;                                                     \
    }                                                                                \
    latb_u[j] = hj;                       /* dup x2 per j: same value, benign */     \
    latb_u += Hn;                         /* uniform -> SALU */                      \
    if (DO_REFILL) {                                                                 \
        XRA = *(const float4*)refp;                                                  \
        XRB = *(const float4*)(refp + 4);                                            \
        refp += In;                       /* uniform -> SALU */                      \
    }                                                                                \
  }

#define KEEP(v) asm volatile("" : "+v"(v))
__attribute__((amdgpu_flat_work_group_size(64, 64), amdgpu_waves_per_eu(1, 1)))
__global__ void gru_kernel(const float* __restrict__ x,     // [B,T,8]
                           const float* __restrict__ Wf,    // [96,8] raw w_ih@E
                           const float* __restrict__ w_hh,  // [96,32]
                           const float* __restrict__ b_ih,  // [96]
                           const float* __restrict__ b_hh,  // [96]
                           float* __restrict__ latents) {   // [B,T,32]
    const int lane   = threadIdx.x & 63;
    const int rowpar = (lane >> 4) & 1;             // K-half = DPP-row parity
    const int j      = (lane & 15) | ((lane >> 1) & 16);  // invariant under ^16
    const int b      = blockIdx.x;

    // ---- probe 1: row_ror permutation (within-row h index per m) ----
    int rho[16];
    {
        float q = (float)(lane & 15);
        rho[0]  = lane & 15;
        rho[1]  = (int)dpp_ror<1>(q);   rho[2]  = (int)dpp_ror<2>(q);
        rho[3]  = (int)dpp_ror<3>(q);   rho[4]  = (int)dpp_ror<4>(q);
        rho[5]  = (int)dpp_ror<5>(q);   rho[6]  = (int)dpp_ror<6>(q);
        rho[7]  = (int)dpp_ror<7>(q);   rho[8]  = (int)dpp_ror<8>(q);
        rho[9]  = (int)dpp_ror<9>(q);   rho[10] = (int)dpp_ror<10>(q);
        rho[11] = (int)dpp_ror<11>(q);  rho[12] = (int)dpp_ror<12>(q);
        rho[13] = (int)dpp_ror<13>(q);  rho[14] = (int)dpp_ror<14>(q);
        rho[15] = (int)dpp_ror<15>(q);
    }
    // ---- probe 2: permlane32_swap output order (which slot = partner) ----
    bool pickr1;
    {
        float t = (float)lane;
        auto rr = __builtin_amdgcn_permlane32_swap(__float_as_int(t),
                                                   __float_as_int(t),
                                                   false, false);
        bool r0_own    = ((int)__int_as_float((int)rr[0]) == lane);
        bool use_swap  = (rowpar != ((lane >> 5) & 1));  // rows 1,2 take partner
        pickr1 = (use_swap == r0_own);
    }

    // ---- recurrent weights: m-th term reads h[16*rowpar + rho[m]] ----
    float whr0,whr1,whr2,whr3,whr4,whr5,whr6,whr7,whr8,whr9,whr10,whr11,whr12,whr13,whr14,whr15;
    float whz0,whz1,whz2,whz3,whz4,whz5,whz6,whz7,whz8,whz9,whz10,whz11,whz12,whz13,whz14,whz15;
    float whn0,whn1,whn2,whn3,whn4,whn5,whn6,whn7,whn8,whn9,whn10,whn11,whn12,whn13,whn14,whn15;
#define LOADW(M)                                                                  \
    {                                                                             \
        const int c = rowpar * 16 + rho[M];                                       \
        whr##M = ALPHA * w_hh[(0*Hn + j)*Hn + c];                                 \
        whz##M = ALPHA * w_hh[(1*Hn + j)*Hn + c];                                 \
        whn##M = BETA  * w_hh[(2*Hn + j)*Hn + c];                                 \
        KEEP(whr##M); KEEP(whz##M); KEEP(whn##M);                                 \
    }
    LOADW(0) LOADW(1) LOADW(2)  LOADW(3)  LOADW(4)  LOADW(5)  LOADW(6)  LOADW(7)
    LOADW(8) LOADW(9) LOADW(10) LOADW(11) LOADW(12) LOADW(13) LOADW(14) LOADW(15)
#undef LOADW

    // ---- input weights: full-8 per lane; r/z pre-halved (halfsum doubles),
    //      n full-scale (anx bypasses the halfsum) ----
    float wxr0,wxr1,wxr2,wxr3,wxr4,wxr5,wxr6,wxr7;
    float wxz0,wxz1,wxz2,wxz3,wxz4,wxz5,wxz6,wxz7;
    float wxn0,wxn1,wxn2,wxn3,wxn4,wxn5,wxn6,wxn7;
#define LOADX(I)                                                                  \
    wxr##I = 0.5f * ALPHA * Wf[(0*Hn + j)*In + I];                                \
    wxz##I = 0.5f * ALPHA * Wf[(1*Hn + j)*In + I];                                \
    wxn##I = BETA         * Wf[(2*Hn + j)*In + I];                                \
    KEEP(wxr##I); KEEP(wxz##I); KEEP(wxn##I);
    LOADX(0) LOADX(1) LOADX(2) LOADX(3) LOADX(4) LOADX(5) LOADX(6) LOADX(7)
#undef LOADX

    // biases: r/z and n-h halved (pass through halfsum16); n-x full
    float br_h  = 0.5f * ALPHA * (b_ih[j]        + b_hh[j]);
    float bz_h  = 0.5f * ALPHA * (b_ih[Hn + j]   + b_hh[Hn + j]);
    float bxn_f = BETA * b_ih[2*Hn + j];
    float bhn_h = 0.5f * BETA * b_hh[2*Hn + j];
    KEEP(br_h); KEEP(bz_h); KEEP(bxn_f); KEEP(bhn_h);

    const float* xb   = x + (size_t)b * Tn * In;
    float* latb_u     = latents + (size_t)b * Tn * Hn;   // uniform base
    const float* refp = xb + 4 * In;                     // next refill = x[4]

    float hj = 0.f;
    float hsrc = 0.f;                                    // h == 0 at t=0

    // ---- 4-deep x ring, uniform addresses (8 floats/step) ----
    float4 a0 = *(const float4*)&xb[0*In], b0 = *(const float4*)&xb[0*In + 4];
    float4 a1 = *(const float4*)&xb[1*In], b1 = *(const float4*)&xb[1*In + 4];
    float4 a2 = *(const float4*)&xb[2*In], b2 = *(const float4*)&xb[2*In + 4];
    float4 a3 = *(const float4*)&xb[3*In], b3 = *(const float4*)&xb[3*In + 4];

    // main loop: steps 0..4091 (1023 groups of 4), refilling x[s+4]
#pragma unroll 1
    for (int s0 = 0; s0 < Tn - 4; s0 += 4) {
        GRU_STEP(a0, b0, a0, b0, true)
        GRU_STEP(a1, b1, a1, b1, true)
        GRU_STEP(a2, b2, a2, b2, true)
        GRU_STEP(a3, b3, a3, b3, true)
    }
    // epilogue: steps 4092..4095 (slots hold x[4092..4095]); no refills
    GRU_STEP(a0, b0, a0, b0, false)
    GRU_STEP(a1, b1, a1, b1, false)
    GRU_STEP(a2, b2, a2, b2, false)
    GRU_STEP(a3, b3, a3, b3, false)
}
#undef KEEP

// outputs[b,t,o] = sum_h latents[b,t,h] * E[h,o]
__global__ void decode_kernel(const float* __restrict__ lat,
                              const float* __restrict__ E,
                              float* __restrict__ out) {
    __shared__ float ldsE[Hn * TGTn];
    int tid = threadIdx.x;
    if (tid < Hn * TGTn) ldsE[tid] = E[tid];
    __syncthreads();
    size_t idx = (size_t)blockIdx.x * 256 + tid;   // over B*T*8
    int o      = (int)(idx & (TGTn - 1));
    size_t row = idx >> 3;
    const float* lrow = lat + row * Hn;
    float acc = 0.f;
#pragma unroll
    for (int h = 0; h < Hn; ++h)
        acc = fmaf(lrow[h], ldsE[h * TGTn + o], acc);
    out[idx] = acc;
}

extern "C" void kernel_launch(void* const* d_in, const int* in_sizes, int n_in,
                              void* d_out, int out_size, void* d_ws, size_t ws_size,
                              hipStream_t stream) {
    const float* x    = (const float*)d_in[0];
    const float* E    = (const float*)d_in[1];
    const float* w_ih = (const float*)d_in[2];
    const float* w_hh = (const float*)d_in[3];
    const float* b_ih = (const float*)d_in[4];
    const float* b_hh = (const float*)d_in[5];

    float* out = (float*)d_out;                          // [B,T,8]
    float* lat = out + (size_t)Bsz * Tn * TGTn;          // [B,T,32]
    float* Wf  = (float*)d_ws;                           // [96,8]

    fuse_wih_kernel<<<1, 768, 0, stream>>>(w_ih, E, Wf);
    gru_kernel<<<Bsz, 64, 0, stream>>>(x, Wf, w_hh, b_ih, b_hh, lat);
    decode_kernel<<<(Bsz * Tn * TGTn) / 256, 256, 0, stream>>>(lat, E, out);
}

// Round 21
// 959.463 us; speedup vs baseline: 1.3359x; 1.3359x over previous
//
#include <hip/hip_runtime.h>
#include <hip/hip_bf16.h>
#include <cstdint>
#include <cstddef>

#define Bsz  256
#define Tn   4096
#define In   8
#define Hn   32
#define TGTn 8

// sigmoid(p) = 1/(1+exp2(ALPHA*p)) with ALPHA = -log2(e)
// tanh path:  exp(2y) = exp2(BETA*y)  with BETA  = 2*log2(e)
#define ALPHA (-1.44269504088896341f)
#define BETA  ( 2.88539008177792682f)

#if __has_builtin(__builtin_amdgcn_exp2f)
__device__ __forceinline__ float exp2f_fast(float x) { return __builtin_amdgcn_exp2f(x); }
#else
__device__ __forceinline__ float exp2f_fast(float x) { return __expf(x * 0.69314718056f); }
#endif
__device__ __forceinline__ float rcpf(float x) { return __builtin_amdgcn_rcpf(x); }

// DPP row_ror via builtin — INIT-TIME PROBE ONLY. ctrl 0x120+N == "row_ror:N",
// the same hardware op the inline-asm fmacs use, so the probed permutation
// matches the hot path exactly.
template<int N>
__device__ __forceinline__ float dpp_ror(float x) {
    int xi = __float_as_int(x);
    int r = __builtin_amdgcn_update_dpp(xi, xi, 0x120 + N, 0xF, 0xF, false);
    return __int_as_float(r);
}

// x_l + x_{l^16}: sum of both permlane16_swap outputs (order-proof).
__device__ __forceinline__ float halfsum16(float x) {
    auto r = __builtin_amdgcn_permlane16_swap(__float_as_int(x), __float_as_int(x),
                                              false, false);
    return __int_as_float((int)r[0]) + __int_as_float((int)r[1]);
}

// fmac with the h-gather FUSED as a DPP row-rotate on src0 (zero extra issue).
#define FMAC_DPP(acc, h, w, N)                                                       \
    asm volatile("v_fmac_f32 %0, %1, %2 row_ror:" #N " row_mask:0xf bank_mask:0xf"   \
                 : "+v"(acc) : "v"(h), "v"(w))
// first DPP of the step: s_nop guards the VALU-write -> DPP-read hazard on hsrc
#define FMAC_DPP_FIRST(acc, h, w, N)                                                 \
    asm volatile("s_nop 1\n\t"                                                       \
                 "v_fmac_f32 %0, %1, %2 row_ror:" #N " row_mask:0xf bank_mask:0xf"   \
                 : "+v"(acc) : "v"(h), "v"(w))

// W = w_ih @ E : [96,8] (raw; scaling applied at gru init)
__global__ void fuse_wih_kernel(const float* __restrict__ w_ih,
                                const float* __restrict__ E,
                                float* __restrict__ Wf) {
    int tid = threadIdx.x;                // 768 threads
    int g = tid >> 3, i = tid & 7;
    float acc = 0.f;
#pragma unroll
    for (int k = 0; k < Hn; ++k)
        acc = fmaf(w_ih[g * Hn + k], E[k * In + i], acc);
    Wf[g * In + i] = acc;
}

// round-robin the three gate chains so dependent fmacs are 3 instrs apart
#define HROT3(N)                                                                     \
    FMAC_DPP(ar,  hsrc, whr##N, N);                                                  \
    FMAC_DPP(az,  hsrc, whz##N, N);                                                  \
    FMAC_DPP(anh, hsrc, whn##N, N);

// One GRU step. XA/XB = x[s] (uniform float4 pair); XRA/XRB = slot refilled
// with x[s+4] when DO_REFILL. hsrc = h[16*rowpar + (lane&15)] per lane.
#define GRU_STEP(XA, XB, XRA, XRB, DO_REFILL)                                        \
  {                                                                                  \
    /* x-dots (full 8 per lane; r/z pre-halved for the halfsum) */                   \
    float ar = br_h, az = bz_h, anx = bxn_f, anh = bhn_h;                            \
    ar  = fmaf(XA.x, wxr0, ar);  ar  = fmaf(XA.y, wxr1, ar);                         \
    ar  = fmaf(XA.z, wxr2, ar);  ar  = fmaf(XA.w, wxr3, ar);                         \
    ar  = fmaf(XB.x, wxr4, ar);  ar  = fmaf(XB.y, wxr5, ar);                         \
    ar  = fmaf(XB.z, wxr6, ar);  ar  = fmaf(XB.w, wxr7, ar);                         \
    az  = fmaf(XA.x, wxz0, az);  az  = fmaf(XA.y, wxz1, az);                         \
    az  = fmaf(XA.z, wxz2, az);  az  = fmaf(XA.w, wxz3, az);                         \
    az  = fmaf(XB.x, wxz4, az);  az  = fmaf(XB.y, wxz5, az);                         \
    az  = fmaf(XB.z, wxz6, az);  az  = fmaf(XB.w, wxz7, az);                         \
    anx = fmaf(XA.x, wxn0, anx); anx = fmaf(XA.y, wxn1, anx);                        \
    anx = fmaf(XA.z, wxn2, anx); anx = fmaf(XA.w, wxn3, anx);                        \
    anx = fmaf(XB.x, wxn4, anx); anx = fmaf(XB.y, wxn5, anx);                        \
    anx = fmaf(XB.z, wxn6, anx); anx = fmaf(XB.w, wxn7, anx);                        \
    /* h-dots with gather fused via DPP; m=0 is plain (also spaces hazard) */        \
    ar  = fmaf(hsrc, whr0, ar);                                                      \
    az  = fmaf(hsrc, whz0, az);                                                      \
    anh = fmaf(hsrc, whn0, anh);                                                     \
    FMAC_DPP_FIRST(ar, hsrc, whr1, 1);                                               \
    FMAC_DPP(az,  hsrc, whz1, 1);                                                    \
    FMAC_DPP(anh, hsrc, whn1, 1);                                                    \
    HROT3(2)  HROT3(3)  HROT3(4)  HROT3(5)  HROT3(6)  HROT3(7)  HROT3(8)             \
    HROT3(9)  HROT3(10) HROT3(11) HROT3(12) HROT3(13) HROT3(14) HROT3(15)            \
    float cr  = halfsum16(ar);            /* ALPHA*(xdot+hdot+bias) */               \
    float cz  = halfsum16(az);                                                       \
    float chn = halfsum16(anh);           /* BETA*(hdot+b_hn)       */               \
    float r = rcpf(1.f + exp2f_fast(cr));                                            \
    float z = rcpf(1.f + exp2f_fast(cz));                                            \
    float e = exp2f_fast(__builtin_fmaf(r, chn, anx));                               \
    float u = rcpf(e + 1.f);                                                         \
    float n = __builtin_fmaf(-2.f, u, 1.f);                                          \
    hj = __builtin_fmaf(z, hj - n, n);                                               \
    /* redistribute: hsrc = h[16*rowpar + (lane&15)] (probed selection) */           \
    {                                                                                \
        auto rr = __builtin_amdgcn_permlane32_swap(__float_as_int(hj),               \
                                                   __float_as_int(hj),               \
                                                   false, false);                    \
        float s0 = __int_as_float((int)rr[0]);                                       \
        float s1 = __int_as_float((int)rr[1]);                                       \
        hsrc = pickr1 ? s1 : s0;                                                     \
    }                                                                                \
    latb_u[j] = hj;                       /* dup x2 per j: same value, benign */     \
    latb_u += Hn;                         /* uniform -> SALU */                      \
    if (DO_REFILL) {                                                                 \
        XRA = *(const float4*)refp;                                                  \
        XRB = *(const float4*)(refp + 4);                                            \
        refp += In;                       /* uniform -> SALU */                      \
    }                                                                                \
  }

#define KEEP(v) asm volatile("" : "+v"(v))
__attribute__((amdgpu_flat_work_group_size(64, 64), amdgpu_waves_per_eu(1, 1)))
__global__ void gru_kernel(const float* __restrict__ x,     // [B,T,8]
                           const float* __restrict__ Wf,    // [96,8] raw w_ih@E
                           const float* __restrict__ w_hh,  // [96,32]
                           const float* __restrict__ b_ih,  // [96]
                           const float* __restrict__ b_hh,  // [96]
                           float* __restrict__ latents) {   // [B,T,32]
    const int lane   = threadIdx.x & 63;
    const int rowpar = (lane >> 4) & 1;             // K-half = DPP-row parity
    const int j      = (lane & 15) | ((lane >> 1) & 16);  // invariant under ^16
    const int b      = blockIdx.x;

    // ---- probe 1: row_ror permutation sigma (within-row h index per m) ----
    int rho[16];
    {
        float q = (float)(lane & 15);
        rho[0]  = lane & 15;
        rho[1]  = (int)dpp_ror<1>(q);   rho[2]  = (int)dpp_ror<2>(q);
        rho[3]  = (int)dpp_ror<3>(q);   rho[4]  = (int)dpp_ror<4>(q);
        rho[5]  = (int)dpp_ror<5>(q);   rho[6]  = (int)dpp_ror<6>(q);
        rho[7]  = (int)dpp_ror<7>(q);   rho[8]  = (int)dpp_ror<8>(q);
        rho[9]  = (int)dpp_ror<9>(q);   rho[10] = (int)dpp_ror<10>(q);
        rho[11] = (int)dpp_ror<11>(q);  rho[12] = (int)dpp_ror<12>(q);
        rho[13] = (int)dpp_ror<13>(q);  rho[14] = (int)dpp_ror<14>(q);
        rho[15] = (int)dpp_ror<15>(q);
    }
    // ---- probe 2: permlane32_swap output order (which slot = partner) ----
    bool pickr1;
    {
        float t = (float)lane;
        auto rr = __builtin_amdgcn_permlane32_swap(__float_as_int(t),
                                                   __float_as_int(t),
                                                   false, false);
        bool r0_own    = ((int)__int_as_float((int)rr[0]) == lane);
        bool use_swap  = (rowpar != ((lane >> 5) & 1));  // rows 1,2 take partner
        pickr1 = (use_swap == r0_own);
    }

    // ---- recurrent weights: m-th fmac reads h[16*rowpar + rho[m]] ----
    float whr0,whr1,whr2,whr3,whr4,whr5,whr6,whr7,whr8,whr9,whr10,whr11,whr12,whr13,whr14,whr15;
    float whz0,whz1,whz2,whz3,whz4,whz5,whz6,whz7,whz8,whz9,whz10,whz11,whz12,whz13,whz14,whz15;
    float whn0,whn1,whn2,whn3,whn4,whn5,whn6,whn7,whn8,whn9,whn10,whn11,whn12,whn13,whn14,whn15;
#define LOADW(M)                                                                  \
    {                                                                             \
        const int c = rowpar * 16 + rho[M];                                       \
        whr##M = ALPHA * w_hh[(0*Hn + j)*Hn + c];                                 \
        whz##M = ALPHA * w_hh[(1*Hn + j)*Hn + c];                                 \
        whn##M = BETA  * w_hh[(2*Hn + j)*Hn + c];                                 \
        KEEP(whr##M); KEEP(whz##M); KEEP(whn##M);                                 \
    }
    LOADW(0) LOADW(1) LOADW(2)  LOADW(3)  LOADW(4)  LOADW(5)  LOADW(6)  LOADW(7)
    LOADW(8) LOADW(9) LOADW(10) LOADW(11) LOADW(12) LOADW(13) LOADW(14) LOADW(15)
#undef LOADW

    // ---- input weights: full-8 per lane; r/z pre-halved (halfsum doubles),
    //      n full-scale (anx bypasses the halfsum) ----
    float wxr0,wxr1,wxr2,wxr3,wxr4,wxr5,wxr6,wxr7;
    float wxz0,wxz1,wxz2,wxz3,wxz4,wxz5,wxz6,wxz7;
    float wxn0,wxn1,wxn2,wxn3,wxn4,wxn5,wxn6,wxn7;
#define LOADX(I)                                                                  \
    wxr##I = 0.5f * ALPHA * Wf[(0*Hn + j)*In + I];                                \
    wxz##I = 0.5f * ALPHA * Wf[(1*Hn + j)*In + I];                                \
    wxn##I = BETA         * Wf[(2*Hn + j)*In + I];                                \
    KEEP(wxr##I); KEEP(wxz##I); KEEP(wxn##I);
    LOADX(0) LOADX(1) LOADX(2) LOADX(3) LOADX(4) LOADX(5) LOADX(6) LOADX(7)
#undef LOADX

    // biases: r/z and n-h halved (pass through halfsum16); n-x full
    float br_h  = 0.5f * ALPHA * (b_ih[j]        + b_hh[j]);
    float bz_h  = 0.5f * ALPHA * (b_ih[Hn + j]   + b_hh[Hn + j]);
    float bxn_f = BETA * b_ih[2*Hn + j];
    float bhn_h = 0.5f * BETA * b_hh[2*Hn + j];
    KEEP(br_h); KEEP(bz_h); KEEP(bxn_f); KEEP(bhn_h);

    const float* xb   = x + (size_t)b * Tn * In;
    float* latb_u     = latents + (size_t)b * Tn * Hn;   // uniform base
    const float* refp = xb + 4 * In;                     // next refill = x[4]

    float hj = 0.f;
    float hsrc = 0.f;                                    // h == 0 at t=0

    // ---- 4-deep x ring, uniform addresses (8 floats/step) ----
    float4 a0 = *(const float4*)&xb[0*In], b0 = *(const float4*)&xb[0*In + 4];
    float4 a1 = *(const float4*)&xb[1*In], b1 = *(const float4*)&xb[1*In + 4];
    float4 a2 = *(const float4*)&xb[2*In], b2 = *(const float4*)&xb[2*In + 4];
    float4 a3 = *(const float4*)&xb[3*In], b3 = *(const float4*)&xb[3*In + 4];

    // main loop: steps 0..4091 (1023 groups of 4), refilling x[s+4]
#pragma unroll 1
    for (int s0 = 0; s0 < Tn - 4; s0 += 4) {
        GRU_STEP(a0, b0, a0, b0, true)
        GRU_STEP(a1, b1, a1, b1, true)
        GRU_STEP(a2, b2, a2, b2, true)
        GRU_STEP(a3, b3, a3, b3, true)
    }
    // epilogue: steps 4092..4095 (slots hold x[4092..4095]); no refills
    GRU_STEP(a0, b0, a0, b0, false)
    GRU_STEP(a1, b1, a1, b1, false)
    GRU_STEP(a2, b2, a2, b2, false)
    GRU_STEP(a3, b3, a3, b3, false)
}
#undef KEEP

// outputs[b,t,o] = sum_h latents[b,t,h] * E[h,o]
__global__ void decode_kernel(const float* __restrict__ lat,
                              const float* __restrict__ E,
                              float* __restrict__ out) {
    __shared__ float ldsE[Hn * TGTn];
    int tid = threadIdx.x;
    if (tid < Hn * TGTn) ldsE[tid] = E[tid];
    __syncthreads();
    size_t idx = (size_t)blockIdx.x * 256 + tid;   // over B*T*8
    int o      = (int)(idx & (TGTn - 1));
    size_t row = idx >> 3;
    const float* lrow = lat + row * Hn;
    float acc = 0.f;
#pragma unroll
    for (int h = 0; h < Hn; ++h)
        acc = fmaf(lrow[h], ldsE[h * TGTn + o], acc);
    out[idx] = acc;
}

extern "C" void kernel_launch(void* const* d_in, const int* in_sizes, int n_in,
                              void* d_out, int out_size, void* d_ws, size_t ws_size,
                              hipStream_t stream) {
    const float* x    = (const float*)d_in[0];
    const float* E    = (const float*)d_in[1];
    const float* w_ih = (const float*)d_in[2];
    const float* w_hh = (const float*)d_in[3];
    const float* b_ih = (const float*)d_in[4];
    const float* b_hh = (const float*)d_in[5];

    float* out = (float*)d_out;                          // [B,T,8]
    float* lat = out + (size_t)Bsz * Tn * TGTn;          // [B,T,32]
    float* Wf  = (float*)d_ws;                           // [96,8]

    fuse_wih_kernel<<<1, 768, 0, stream>>>(w_ih, E, Wf);
    gru_kernel<<<Bsz, 64, 0, stream>>>(x, Wf, w_hh, b_ih, b_hh, lat);
    decode_kernel<<<(Bsz * Tn * TGTn) / 256, 256, 0, stream>>>(lat, E, out);
}